// Round 14
// baseline (61863.788 us; speedup 1.0000x reference)
//
#include <hip/hip_runtime.h>

#define S_LEN 4096
#define BATCH 16
#define HDIM  512
#define OUT_MAIN ((size_t)BATCH * S_LEN * HDIM)   // 33,554,432 f32 elements

// Float32 scan replicating the numpy reference's arithmetic exactly:
//   hc = h @ Wh + bh : sequential-k FMA chain (BLAS sgemm), then one fadd of bh
//   ic = x @ Wi + bi : sequential-d mul+add (np.einsum naive loop), then one fadd
//   update chain     : separate rounded f32 ops (no contraction), np op order
// One block per batch, 512 threads = one channel j each, sequential k => exact
// reproduction of per-element accumulation order.
__global__ __launch_bounds__(512, 2)
void scan_f32(const float* __restrict__ x, const float* __restrict__ Wi,
              const float* __restrict__ bi, const float* __restrict__ Wh,
              const float* __restrict__ bh, unsigned char* __restrict__ spk,
              float* __restrict__ out)
{
    const int b = blockIdx.x;
    const int j = threadIdx.x;

    __shared__ float h_lds[HDIM];
    __shared__ float x_lds[HDIM];

    float v = 0.0f, hn = 0.0f, sp = 0.0f;
    const float rbh = bh[j], rbi = bi[j];
    h_lds[j] = 0.0f;

    const float* xb = x + (size_t)b * S_LEN * HDIM;

    for (int t = 0; t < S_LEN; ++t) {
        // stage x_t (prev iteration's reads completed at loop-end barrier)
        x_lds[j] = xb[(size_t)t * HDIM + j];
        __syncthreads();

        // sequential-k dots for channel j (two independent chains interleave)
        float ah = 0.0f, ax = 0.0f;
        const float* wj = Wh + j;
        const float* qj = Wi + j;
#pragma unroll 8
        for (int k = 0; k < HDIM; ++k) {
            ah = __fmaf_rn(h_lds[k], wj[(size_t)k * HDIM], ah);                  // sgemm: FMA chain
            ax = __fadd_rn(ax, __fmul_rn(x_lds[k], qj[(size_t)k * HDIM]));       // einsum: mul+add
        }
        const float hc = __fadd_rn(ah, rbh);      // (h@Wh) + bh
        const float ic = __fadd_rn(ax, rbi);      // (x@Wi) + bi

        const float ho = h_lds[j];
        const float t1 = __fadd_rn(-ho, ic);      // -h + ic
        const float t2 = __fadd_rn(t1, hc);       // ... + hc
        const float t3 = __fmul_rn(t2, 0.1f);     // * inv_tau (f32)
        hn = __fadd_rn(ho, t3);                   // h + ...

        const float u1 = __fadd_rn(-v, hn);       // -v + h_new
        const float u2 = __fmul_rn(u1, 0.1f);
        const float vn = __fadd_rn(v, u2);

        sp = (vn >= 1.0f) ? 1.0f : 0.0f;
        v  = (vn >= 1.0f) ? 0.0f : vn;

        spk[((size_t)t * BATCH + b) * HDIM + j] = (unsigned char)sp;

        __syncthreads();          // all dot-reads of h_lds done
        h_lds[j] = hn;
        __syncthreads();          // h_{t+1} visible before next dot
    }

    // tails: h_f, v_f, spikes_last (f32, chunk offsets per harness concat)
    out[OUT_MAIN + (size_t)b * HDIM + j]          = hn;
    out[OUT_MAIN + 8192 + (size_t)b * HDIM + j]   = v;
    out[OUT_MAIN + 16384 + (size_t)b * HDIM + j]  = sp;
}

// outputs[b,s,d] = sum_h spikes[s,b,h] * Wo[h*512+d] + bo[d]   (einsum 'sbh,hd->bsd')
__global__ __launch_bounds__(256, 2)
void out_gemm(const unsigned char* __restrict__ spikes, const float* __restrict__ Wo,
              const float* __restrict__ bo, float* __restrict__ out)
{
    const int s0 = blockIdx.x * 64;
    const int d0 = blockIdx.y * 64;
    const int b  = blockIdx.z;
    const int tid = threadIdx.x;

    __shared__ float sA[32][68];  // [k][m] spikes
    __shared__ float sB[32][68];  // [k][n] Wo

    float acc[4][4] = {};
    const int tm = tid >> 4, tn = tid & 15;
    const int m0 = tm * 4, n0 = tn * 4;

    for (int k0 = 0; k0 < HDIM; k0 += 32) {
        {
            const int m = tid >> 2, kq = (tid & 3) * 8;
            const unsigned char* pp = spikes + ((size_t)(s0 + m) * BATCH + b) * HDIM + k0 + kq;
            uchar4 u0 = *(const uchar4*)pp;
            uchar4 u1 = *(const uchar4*)(pp + 4);
            sA[kq+0][m] = (float)u0.x; sA[kq+1][m] = (float)u0.y;
            sA[kq+2][m] = (float)u0.z; sA[kq+3][m] = (float)u0.w;
            sA[kq+4][m] = (float)u1.x; sA[kq+5][m] = (float)u1.y;
            sA[kq+6][m] = (float)u1.z; sA[kq+7][m] = (float)u1.w;
        }
        {
            const int k = tid >> 3, n8 = (tid & 7) * 8;
            const float* pw = Wo + (size_t)(k0 + k) * HDIM + d0 + n8;
            float4 v0 = *(const float4*)pw;
            float4 v1 = *(const float4*)(pw + 4);
            *(float4*)&sB[k][n8]     = v0;
            *(float4*)&sB[k][n8 + 4] = v1;
        }
        __syncthreads();
#pragma unroll
        for (int k = 0; k < 32; ++k) {
            float a0 = sA[k][m0+0], a1 = sA[k][m0+1], a2 = sA[k][m0+2], a3 = sA[k][m0+3];
            float b0v = sB[k][n0+0], b1v = sB[k][n0+1], b2v = sB[k][n0+2], b3v = sB[k][n0+3];
            acc[0][0] += a0*b0v; acc[0][1] += a0*b1v; acc[0][2] += a0*b2v; acc[0][3] += a0*b3v;
            acc[1][0] += a1*b0v; acc[1][1] += a1*b1v; acc[1][2] += a1*b2v; acc[1][3] += a1*b3v;
            acc[2][0] += a2*b0v; acc[2][1] += a2*b1v; acc[2][2] += a2*b2v; acc[2][3] += a2*b3v;
            acc[3][0] += a3*b0v; acc[3][1] += a3*b1v; acc[3][2] += a3*b2v; acc[3][3] += a3*b3v;
        }
        __syncthreads();
    }

    float bov[4];
#pragma unroll
    for (int j = 0; j < 4; ++j) bov[j] = bo[d0 + n0 + j];
#pragma unroll
    for (int i = 0; i < 4; ++i) {
        size_t row = (size_t)b * S_LEN + s0 + m0 + i;
        float* o = out + row * HDIM + d0 + n0;
#pragma unroll
        for (int j = 0; j < 4; ++j)
            o[j] = acc[i][j] + bov[j];
    }
}

extern "C" void kernel_launch(void* const* d_in, const int* in_sizes, int n_in,
                              void* d_out, int out_size, void* d_ws, size_t ws_size,
                              hipStream_t stream)
{
    const float* x  = (const float*)d_in[0];
    const float* Wi = (const float*)d_in[1];
    const float* bi = (const float*)d_in[2];
    const float* Wh = (const float*)d_in[3];
    const float* bh = (const float*)d_in[4];
    const float* Wo = (const float*)d_in[5];
    const float* bo = (const float*)d_in[6];
    float* out = (float*)d_out;                     // FLOAT32 output buffer

    unsigned char* spikes = (unsigned char*)d_ws;   // [S][B][H] u8

    scan_f32<<<dim3(BATCH), dim3(512), 0, stream>>>(x, Wi, bi, Wh, bh, spikes, out);

    out_gemm<<<dim3(S_LEN / 64, HDIM / 64, BATCH), dim3(256), 0, stream>>>(spikes, Wo, bo, out);
}